// Round 1
// baseline (608.739 us; speedup 1.0000x reference)
//
#include <hip/hip_runtime.h>

// Problem constants
#define N_ROWS   32768      // 64*512 flattened z rows
#define KCODES   1024
#define DDIM     256

// d_out float offsets (outputs concatenated in reference return order)
#define O_ZQ     0                    // 8388608
#define O_LOSS   8388608              // 1
#define O_IDX    8388609              // 32768
#define O_NCS    8421377              // 1024
#define O_NEA    8422401              // 262144
#define O_NEMB   8684545              // 262144

// workspace float offsets
#define W_ESUM   0                    // 262144 floats (zeroed)
#define W_COUNTS 262144               // 1024 floats  (zeroed)
#define W_LOSS   263168               // 1 float      (zeroed)
#define W_N      263169               // 1 float      (zeroed)
#define W_ENORM  263680               // 1024 floats  (written by k_enorm)
#define W_IDX    264704               // 32768 ints   (written by k_argmin)
// total ws floats = 297472 -> ~1.16 MB

// ---------------------------------------------------------------------------
// ||e_k||^2 for each code. 1024 blocks x 64 threads (1 wave per code).
__global__ __launch_bounds__(64)
void k_enorm(const float* __restrict__ emb, float* __restrict__ enorm) {
    int c = blockIdx.x;
    int t = threadIdx.x;
    float4 v = *(const float4*)(emb + c * DDIM + t * 4);
    float s = v.x * v.x + v.y * v.y + v.z * v.z + v.w * v.w;
    #pragma unroll
    for (int off = 32; off > 0; off >>= 1) s += __shfl_down(s, off);
    if (t == 0) enorm[c] = s;
}

// ---------------------------------------------------------------------------
// Argmin over codes. Block = 64 rows x 64-code tiles, 256 threads, 4x4 micro.
// dist(r,c) = ||e_c||^2 - 2 * z_r . e_c   (||z_r||^2 dropped: row-constant)
#define FMA4(ACC, S, B)                      \
    ACC.x = fmaf((S), (B).x, ACC.x);         \
    ACC.y = fmaf((S), (B).y, ACC.y);         \
    ACC.z = fmaf((S), (B).z, ACC.z);         \
    ACC.w = fmaf((S), (B).w, ACC.w);

__global__ __launch_bounds__(256)
void k_argmin(const float* __restrict__ z, const float* __restrict__ emb,
              const float* __restrict__ enorm,
              int* __restrict__ out_idx, float* __restrict__ out_idx_f) {
    // zs: row-major [row][dim] stride 68 (reads are ty-broadcast -> conflict-free)
    // es: transposed [dim][code] stride 68 (b128 read across 16 lanes spreads banks)
    __shared__ float zs[64 * 68];
    __shared__ float es[64 * 68];

    const int tid = threadIdx.x;
    const int tx = tid & 15;          // code group (in-wave, 16 lanes)
    const int ty = tid >> 4;          // row group
    const int rbase = blockIdx.x * 64;

    float best_d[4];
    int   best_i[4];
    #pragma unroll
    for (int i = 0; i < 4; ++i) { best_d[i] = 3.402823466e38f; best_i[i] = 0; }

    for (int ct = 0; ct < 16; ++ct) {          // 16 code tiles of 64
        const int cbase = ct * 64;
        float4 acc0 = {0.f,0.f,0.f,0.f}, acc1 = {0.f,0.f,0.f,0.f};
        float4 acc2 = {0.f,0.f,0.f,0.f}, acc3 = {0.f,0.f,0.f,0.f};

        for (int kc = 0; kc < 4; ++kc) {       // 4 dim chunks of 64
            __syncthreads();
            #pragma unroll
            for (int q = 0; q < 4; ++q) {      // stage 64x64 of z and e
                int f   = tid + q * 256;
                int row = f >> 4;              // 0..63
                int dq  = f & 15;              // 0..15 (float4 within chunk)
                float4 zv = *(const float4*)(z + (size_t)(rbase + row) * DDIM + kc * 64 + dq * 4);
                *(float4*)(&zs[row * 68 + dq * 4]) = zv;
                float4 ev = *(const float4*)(emb + (size_t)(cbase + row) * DDIM + kc * 64 + dq * 4);
                es[(dq * 4 + 0) * 68 + row] = ev.x;
                es[(dq * 4 + 1) * 68 + row] = ev.y;
                es[(dq * 4 + 2) * 68 + row] = ev.z;
                es[(dq * 4 + 3) * 68 + row] = ev.w;
            }
            __syncthreads();

            #pragma unroll 4
            for (int kk = 0; kk < 64; kk += 4) {
                float4 a0 = *(const float4*)(&zs[(4 * ty + 0) * 68 + kk]);
                float4 a1 = *(const float4*)(&zs[(4 * ty + 1) * 68 + kk]);
                float4 a2 = *(const float4*)(&zs[(4 * ty + 2) * 68 + kk]);
                float4 a3 = *(const float4*)(&zs[(4 * ty + 3) * 68 + kk]);
                float4 b0 = *(const float4*)(&es[(kk + 0) * 68 + 4 * tx]);
                float4 b1 = *(const float4*)(&es[(kk + 1) * 68 + 4 * tx]);
                float4 b2 = *(const float4*)(&es[(kk + 2) * 68 + 4 * tx]);
                float4 b3 = *(const float4*)(&es[(kk + 3) * 68 + 4 * tx]);
                FMA4(acc0, a0.x, b0); FMA4(acc0, a0.y, b1); FMA4(acc0, a0.z, b2); FMA4(acc0, a0.w, b3);
                FMA4(acc1, a1.x, b0); FMA4(acc1, a1.y, b1); FMA4(acc1, a1.z, b2); FMA4(acc1, a1.w, b3);
                FMA4(acc2, a2.x, b0); FMA4(acc2, a2.y, b1); FMA4(acc2, a2.z, b2); FMA4(acc2, a2.w, b3);
                FMA4(acc3, a3.x, b0); FMA4(acc3, a3.y, b1); FMA4(acc3, a3.z, b2); FMA4(acc3, a3.w, b3);
            }
        }

        // fold this code tile into the running argmin (ascending col, strict <)
        float4 en = *(const float4*)(enorm + cbase + 4 * tx);
        float4 accs[4] = {acc0, acc1, acc2, acc3};
        #pragma unroll
        for (int i = 0; i < 4; ++i) {
            float d0 = fmaf(-2.f, accs[i].x, en.x);
            float d1 = fmaf(-2.f, accs[i].y, en.y);
            float d2 = fmaf(-2.f, accs[i].z, en.z);
            float d3 = fmaf(-2.f, accs[i].w, en.w);
            int c0 = cbase + 4 * tx;
            if (d0 < best_d[i]) { best_d[i] = d0; best_i[i] = c0;     }
            if (d1 < best_d[i]) { best_d[i] = d1; best_i[i] = c0 + 1; }
            if (d2 < best_d[i]) { best_d[i] = d2; best_i[i] = c0 + 2; }
            if (d3 < best_d[i]) { best_d[i] = d3; best_i[i] = c0 + 3; }
        }
    }

    // reduce across the 16 lanes (tx) sharing each row; ties -> smaller index
    #pragma unroll
    for (int i = 0; i < 4; ++i) {
        float d = best_d[i];
        int   b = best_i[i];
        #pragma unroll
        for (int off = 8; off > 0; off >>= 1) {
            float od = __shfl_xor(d, off);
            int   ob = __shfl_xor(b, off);
            if (od < d || (od == d && ob < b)) { d = od; b = ob; }
        }
        best_d[i] = d; best_i[i] = b;
    }
    if (tx == 0) {
        #pragma unroll
        for (int i = 0; i < 4; ++i) {
            int r = rbase + 4 * ty + i;
            out_idx[r]   = best_i[i];
            out_idx_f[r] = (float)best_i[i];
        }
    }
}

// ---------------------------------------------------------------------------
// Gather z_q, write z_q_st = z + (z_q - z), loss partials, segment-sum atomics.
// Block = 256 threads = 4 rows x 64 lanes (4 dims/lane).
__global__ __launch_bounds__(256)
void k_scatter(const float* __restrict__ z, const float* __restrict__ emb,
               const int* __restrict__ idx, float* __restrict__ out_zq,
               float* __restrict__ counts, float* __restrict__ esum,
               float* __restrict__ loss_acc) {
    int tid  = threadIdx.x;
    int rl   = tid >> 6;
    int lane = tid & 63;
    int row  = blockIdx.x * 4 + rl;
    int k    = idx[row];

    float4 zv = *(const float4*)(z   + (size_t)row * DDIM + lane * 4);
    float4 ev = *(const float4*)(emb + (size_t)k   * DDIM + lane * 4);
    float dx = ev.x - zv.x, dy = ev.y - zv.y, dz = ev.z - zv.z, dw = ev.w - zv.w;
    float4 o;
    o.x = zv.x + dx; o.y = zv.y + dy; o.z = zv.z + dz; o.w = zv.w + dw;  // z + (z_q - z), ref op order
    *(float4*)(out_zq + (size_t)row * DDIM + lane * 4) = o;

    float l = dx * dx + dy * dy + dz * dz + dw * dw;

    atomicAdd(esum + (size_t)k * DDIM + lane * 4 + 0, zv.x);
    atomicAdd(esum + (size_t)k * DDIM + lane * 4 + 1, zv.y);
    atomicAdd(esum + (size_t)k * DDIM + lane * 4 + 2, zv.z);
    atomicAdd(esum + (size_t)k * DDIM + lane * 4 + 3, zv.w);
    if (lane == 0) atomicAdd(counts + k, 1.0f);

    #pragma unroll
    for (int off = 32; off > 0; off >>= 1) l += __shfl_down(l, off);
    __shared__ float ls[4];
    if (lane == 0) ls[rl] = l;
    __syncthreads();
    if (tid == 0) atomicAdd(loss_acc, ls[0] + ls[1] + ls[2] + ls[3]);
}

// ---------------------------------------------------------------------------
__global__ __launch_bounds__(256)
void k_ncs(const float* __restrict__ cs_in, const float* __restrict__ counts,
           float* __restrict__ out_ncs) {
    int k = blockIdx.x * 256 + threadIdx.x;
    out_ncs[k] = cs_in[k] * 0.99f + 0.01f * counts[k];
}

__global__ __launch_bounds__(256)
void k_nsum(const float* __restrict__ ncs, const float* __restrict__ loss_acc,
            float* __restrict__ n_out, float* __restrict__ loss_out) {
    float v = 0.f;
    for (int i = threadIdx.x; i < KCODES; i += 256) v += ncs[i];
    #pragma unroll
    for (int off = 32; off > 0; off >>= 1) v += __shfl_down(v, off);
    __shared__ float s[4];
    if ((threadIdx.x & 63) == 0) s[threadIdx.x >> 6] = v;
    __syncthreads();
    if (threadIdx.x == 0) {
        n_out[0]    = s[0] + s[1] + s[2] + s[3];
        loss_out[0] = 0.25f * (loss_acc[0] / 8388608.0f);
    }
}

__global__ __launch_bounds__(256)
void k_embed(const float* __restrict__ ea, const float* __restrict__ esum,
             const float* __restrict__ ncs, const float* __restrict__ n_ws,
             float* __restrict__ out_nea, float* __restrict__ out_nemb) {
    int k = blockIdx.x;
    int d = threadIdx.x;
    size_t off = (size_t)k * DDIM + d;
    float nea = ea[off] * 0.99f + 0.01f * esum[off];
    out_nea[off] = nea;
    float cs = (ncs[k] + 1e-6f) / (n_ws[0] + 0.001024f);   // (ncs+eps)/(n+K*eps)
    out_nemb[off] = nea / cs;
}

// ---------------------------------------------------------------------------
extern "C" void kernel_launch(void* const* d_in, const int* in_sizes, int n_in,
                              void* d_out, int out_size, void* d_ws, size_t ws_size,
                              hipStream_t stream) {
    const float* z   = (const float*)d_in[0];
    const float* emb = (const float*)d_in[1];
    const float* cs  = (const float*)d_in[2];
    const float* ea  = (const float*)d_in[3];
    float* out = (float*)d_out;
    float* ws  = (float*)d_ws;

    float* esum   = ws + W_ESUM;
    float* counts = ws + W_COUNTS;
    float* wloss  = ws + W_LOSS;
    float* wn     = ws + W_N;
    float* enorm  = ws + W_ENORM;
    int*   widx   = (int*)(ws + W_IDX);

    // zero esum + counts + loss + n (ws is poisoned 0xAA before every call)
    hipMemsetAsync(ws, 0, (size_t)(W_N + 1) * sizeof(float), stream);

    k_enorm  <<<KCODES, 64, 0, stream>>>(emb, enorm);
    k_argmin <<<N_ROWS / 64, 256, 0, stream>>>(z, emb, enorm, widx, out + O_IDX);
    k_scatter<<<N_ROWS / 4, 256, 0, stream>>>(z, emb, widx, out + O_ZQ, counts, esum, wloss);
    k_ncs    <<<KCODES / 256, 256, 0, stream>>>(cs, counts, out + O_NCS);
    k_nsum   <<<1, 256, 0, stream>>>(out + O_NCS, wloss, wn, out + O_LOSS);
    k_embed  <<<KCODES, 256, 0, stream>>>(ea, esum, out + O_NCS, wn, out + O_NEA, out + O_NEMB);
}

// Round 2
// 555.062 us; speedup vs baseline: 1.0967x; 1.0967x over previous
//
#include <hip/hip_runtime.h>

// Problem constants
#define N_ROWS   32768      // 64*512 flattened z rows
#define KCODES   1024
#define DDIM     256

// d_out float offsets (outputs concatenated in reference return order)
#define O_ZQ     0                    // 8388608
#define O_LOSS   8388608              // 1
#define O_IDX    8388609              // 32768
#define O_NCS    8421377              // 1024
#define O_NEA    8422401              // 262144
#define O_NEMB   8684545              // 262144

// workspace float offsets (lossp aliases enorm: enorm is dead after k_argmin,
// lossp is written by k_zq which is stream-ordered after k_argmin)
#define W_ESUM   0                    // 262144 floats (fully written by k_gathersum)
#define W_COUNTS 262144               // 1024 floats  (fully written by k_gathersum)
#define W_ENORM  263168               // 1024 floats  (k_enorm -> k_argmin)
#define W_LOSSP  263168               // 1024 floats  (k_zq -> k_nsum), aliases enorm
#define W_IDX    264192               // 32768 ints   (k_argmin -> k_zq/k_gathersum)
// total = 296960 floats (~1.13 MB), within round-1 proven ws footprint

// ---------------------------------------------------------------------------
// ||e_k||^2 for each code. 1024 blocks x 64 threads (1 wave per code).
__global__ __launch_bounds__(64)
void k_enorm(const float* __restrict__ emb, float* __restrict__ enorm) {
    int c = blockIdx.x;
    int t = threadIdx.x;
    float4 v = *(const float4*)(emb + c * DDIM + t * 4);
    float s = v.x * v.x + v.y * v.y + v.z * v.z + v.w * v.w;
    #pragma unroll
    for (int off = 32; off > 0; off >>= 1) s += __shfl_down(s, off);
    if (t == 0) enorm[c] = s;
}

// ---------------------------------------------------------------------------
// Argmin over codes. Block = 64 rows x full K, 256 threads, 4x4 micro-tile.
// dist(r,c) = ||e_c||^2 - 2 * z_r . e_c   (||z_r||^2 dropped: row-constant)
//
// LDS layout (exactly 80 KB -> 2 blocks/CU):
//   zs[64][256] row-major, per-row XOR swizzle col^=(r&7)*4   (staged ONCE)
//   es[64][64]  row-major, per-row XOR swizzle col^=((c>>2)&7)*4 (per tile)
// Both staged with float4 stores (conflict-free: each 16-lane group covers a
// permuted contiguous 64-float row). a-reads: 16-lane broadcast, 2-way bank
// alias (free). b-reads: 16 distinct b128 over 8 bank-groups, 2-way (free).
// e-tiles are register-prefetched one phase ahead so L3 latency hides under
// the ~2k-cycle compute phase instead of stalling every barrier.
__global__ __launch_bounds__(256)
void k_argmin(const float* __restrict__ z, const float* __restrict__ emb,
              const float* __restrict__ enorm,
              int* __restrict__ out_idx, float* __restrict__ out_idx_f) {
    __shared__ float zs[64 * 256];
    __shared__ float es[64 * 64];

    const int tid = threadIdx.x;
    const int tx = tid & 15;          // code group (16 lanes, 4 codes each)
    const int ty = tid >> 4;          // row group (4 rows each)
    const int rbase = blockIdx.x * 64;
    const int swb = (tx & 7) * 4;     // b-read swizzle for this thread's codes

    // ---- stage z once: 64 rows x 256 dims, swizzled
    #pragma unroll
    for (int q = 0; q < 16; ++q) {
        int f  = tid + q * 256;
        int r  = f >> 6;              // 0..63
        int dq = f & 63;              // float4 within row
        float4 v = *(const float4*)(z + (size_t)(rbase + r) * DDIM + dq * 4);
        int col = (dq * 4) ^ ((r & 7) * 4);
        *(float4*)(&zs[r * 256 + col]) = v;
    }

    // ---- prefetch e tile 0 (ct=0, kc=0)
    float4 ev[4];
    #pragma unroll
    for (int q = 0; q < 4; ++q) {
        int f = tid + q * 256;
        int r = f >> 4, dq = f & 15;
        ev[q] = *(const float4*)(emb + (size_t)r * DDIM + dq * 4);
    }

    float best_d[4];
    int   best_i[4];
    #pragma unroll
    for (int i = 0; i < 4; ++i) { best_d[i] = 3.402823466e38f; best_i[i] = 0; }
    float acc[4][4];
    #pragma unroll
    for (int i = 0; i < 4; ++i)
        #pragma unroll
        for (int j = 0; j < 4; ++j) acc[i][j] = 0.f;

    for (int p = 0; p < 64; ++p) {         // phase = (code tile ct = p>>2, dim chunk kc = p&3)
        const int kc = p & 3;
        __syncthreads();                   // readers done with old es
        #pragma unroll
        for (int q = 0; q < 4; ++q) {      // store prefetched tile
            int f = tid + q * 256;
            int r = f >> 4, dq = f & 15;
            int col = (dq * 4) ^ (((r >> 2) & 7) * 4);
            *(float4*)(&es[r * 64 + col]) = ev[q];
        }
        __syncthreads();
        if (p < 63) {                      // issue next tile's loads (uniform branch)
            int pn = p + 1;
            int ctn = pn >> 2, kcn = pn & 3;
            #pragma unroll
            for (int q = 0; q < 4; ++q) {
                int f = tid + q * 256;
                int r = f >> 4, dq = f & 15;
                ev[q] = *(const float4*)(emb + (size_t)(ctn * 64 + r) * DDIM + kcn * 64 + dq * 4);
            }
        }

        // compute: dims [kc*64, kc*64+64) x this thread's 4 rows x 4 codes
        #pragma unroll 4
        for (int kk = 0; kk < 64; kk += 4) {
            const int db = kc * 64 + kk;
            float4 a[4], b[4];
            #pragma unroll
            for (int i = 0; i < 4; ++i) {
                int rr = 4 * ty + i;
                a[i] = *(const float4*)(&zs[rr * 256 + (db ^ ((rr & 7) * 4))]);
            }
            #pragma unroll
            for (int j = 0; j < 4; ++j)
                b[j] = *(const float4*)(&es[(4 * tx + j) * 64 + (kk ^ swb)]);
            #pragma unroll
            for (int i = 0; i < 4; ++i)
                #pragma unroll
                for (int j = 0; j < 4; ++j) {
                    acc[i][j] = fmaf(a[i].x, b[j].x, acc[i][j]);
                    acc[i][j] = fmaf(a[i].y, b[j].y, acc[i][j]);
                    acc[i][j] = fmaf(a[i].z, b[j].z, acc[i][j]);
                    acc[i][j] = fmaf(a[i].w, b[j].w, acc[i][j]);
                }
        }

        if ((p & 3) == 3) {                // code tile complete: fold argmin
            const int cbase = (p >> 2) * 64;
            float4 en = *(const float4*)(enorm + cbase + 4 * tx);
            const int c0 = cbase + 4 * tx;
            #pragma unroll
            for (int i = 0; i < 4; ++i) {
                float d0 = fmaf(-2.f, acc[i][0], en.x);
                float d1 = fmaf(-2.f, acc[i][1], en.y);
                float d2 = fmaf(-2.f, acc[i][2], en.z);
                float d3 = fmaf(-2.f, acc[i][3], en.w);
                if (d0 < best_d[i]) { best_d[i] = d0; best_i[i] = c0;     }
                if (d1 < best_d[i]) { best_d[i] = d1; best_i[i] = c0 + 1; }
                if (d2 < best_d[i]) { best_d[i] = d2; best_i[i] = c0 + 2; }
                if (d3 < best_d[i]) { best_d[i] = d3; best_i[i] = c0 + 3; }
                acc[i][0] = acc[i][1] = acc[i][2] = acc[i][3] = 0.f;
            }
        }
    }

    // reduce across the 16 lanes (tx) sharing each row; ties -> smaller index
    #pragma unroll
    for (int i = 0; i < 4; ++i) {
        float d = best_d[i];
        int   bI = best_i[i];
        #pragma unroll
        for (int off = 8; off > 0; off >>= 1) {
            float od = __shfl_xor(d, off);
            int   ob = __shfl_xor(bI, off);
            if (od < d || (od == d && ob < bI)) { d = od; bI = ob; }
        }
        best_d[i] = d; best_i[i] = bI;
    }
    if (tx == 0) {
        #pragma unroll
        for (int i = 0; i < 4; ++i) {
            int r = rbase + 4 * ty + i;
            out_idx[r]   = best_i[i];
            out_idx_f[r] = (float)best_i[i];
        }
    }
}

// ---------------------------------------------------------------------------
// Streaming z_q gather + z_q_st write + commitment-loss partials (no atomics).
// 1024 blocks x 256 threads x 8 float4 = 2,097,152 float4 = 32768x256 floats.
__global__ __launch_bounds__(256)
void k_zq(const float* __restrict__ z, const float* __restrict__ emb,
          const int* __restrict__ idx, float* __restrict__ out_zq,
          float* __restrict__ lossp) {
    const int tid = threadIdx.x;
    float l = 0.f;
    #pragma unroll
    for (int u = 0; u < 8; ++u) {
        int g   = blockIdx.x * 2048 + u * 256 + tid;  // float4 index
        int row = g >> 6;
        int c4  = g & 63;
        int k   = idx[row];                            // wave-uniform
        float4 zv = *(const float4*)(z   + (size_t)row * DDIM + c4 * 4);
        float4 ev = *(const float4*)(emb + (size_t)k   * DDIM + c4 * 4);
        float dx = ev.x - zv.x, dy = ev.y - zv.y, dz = ev.z - zv.z, dw = ev.w - zv.w;
        float4 o = { zv.x + dx, zv.y + dy, zv.z + dz, zv.w + dw };  // z + (z_q - z)
        *(float4*)(out_zq + (size_t)g * 4) = o;
        l += dx * dx + dy * dy + dz * dz + dw * dw;
    }
    #pragma unroll
    for (int off = 32; off > 0; off >>= 1) l += __shfl_down(l, off);
    __shared__ float ls[4];
    if ((tid & 63) == 0) ls[tid >> 6] = l;
    __syncthreads();
    if (tid == 0) lossp[blockIdx.x] = ls[0] + ls[1] + ls[2] + ls[3];
}

// ---------------------------------------------------------------------------
// Segment-sum as gather: one block per code, 4 waves scan disjoint quarters of
// idx via ballot; matching rows' z vectors accumulated coalesced. No atomics.
__global__ __launch_bounds__(256)
void k_gathersum(const float* __restrict__ z, const int* __restrict__ idx,
                 float* __restrict__ esum, float* __restrict__ counts) {
    const int code = blockIdx.x;
    const int tid  = threadIdx.x;
    const int w    = tid >> 6;
    const int lane = tid & 63;
    const int seg  = w * (N_ROWS / 4);

    float4 acc = {0.f, 0.f, 0.f, 0.f};
    int cnt = 0;
    #pragma unroll 4
    for (int b = 0; b < N_ROWS / 4; b += 64) {
        int v = idx[seg + b + lane];
        unsigned long long m = __ballot(v == code);
        cnt += __popcll(m);                       // wave-uniform
        while (m) {                               // avg 0.03 matches/batch
            int bit = __builtin_ctzll(m);
            m &= m - 1;
            int rr = seg + b + bit;
            float4 zv = *(const float4*)(z + (size_t)rr * DDIM + lane * 4);
            acc.x += zv.x; acc.y += zv.y; acc.z += zv.z; acc.w += zv.w;
        }
    }

    __shared__ float sacc[4][DDIM];
    __shared__ int   scnt[4];
    *(float4*)(&sacc[w][lane * 4]) = acc;
    if (lane == 0) scnt[w] = cnt;
    __syncthreads();
    float s = sacc[0][tid] + sacc[1][tid] + sacc[2][tid] + sacc[3][tid];
    esum[(size_t)code * DDIM + tid] = s;
    if (tid == 0) counts[code] = (float)(scnt[0] + scnt[1] + scnt[2] + scnt[3]);
}

// ---------------------------------------------------------------------------
__global__ __launch_bounds__(256)
void k_ncs(const float* __restrict__ cs_in, const float* __restrict__ counts,
           float* __restrict__ out_ncs) {
    int k = blockIdx.x * 256 + threadIdx.x;
    out_ncs[k] = cs_in[k] * 0.99f + 0.01f * counts[k];
}

__global__ __launch_bounds__(256)
void k_nsum(const float* __restrict__ ncs, const float* __restrict__ lossp,
            float* __restrict__ n_out, float* __restrict__ loss_out) {
    const int tid = threadIdx.x;
    float v = 0.f, l = 0.f;
    for (int i = tid; i < KCODES; i += 256) { v += ncs[i]; l += lossp[i]; }
    #pragma unroll
    for (int off = 32; off > 0; off >>= 1) {
        v += __shfl_down(v, off);
        l += __shfl_down(l, off);
    }
    __shared__ float sv[4], sl[4];
    if ((tid & 63) == 0) { sv[tid >> 6] = v; sl[tid >> 6] = l; }
    __syncthreads();
    if (tid == 0) {
        n_out[0]    = sv[0] + sv[1] + sv[2] + sv[3];
        loss_out[0] = 0.25f * ((sl[0] + sl[1] + sl[2] + sl[3]) / 8388608.0f);
    }
}

__global__ __launch_bounds__(256)
void k_embed(const float* __restrict__ ea, const float* __restrict__ esum,
             const float* __restrict__ ncs, const float* __restrict__ n_ws,
             float* __restrict__ out_nea, float* __restrict__ out_nemb) {
    int k = blockIdx.x;
    int d = threadIdx.x;
    size_t off = (size_t)k * DDIM + d;
    float nea = ea[off] * 0.99f + 0.01f * esum[off];
    out_nea[off] = nea;
    float cs = (ncs[k] + 1e-6f) / (n_ws[0] + 0.001024f);   // (ncs+eps)/(n+K*eps)
    out_nemb[off] = nea / cs;
}

// ---------------------------------------------------------------------------
extern "C" void kernel_launch(void* const* d_in, const int* in_sizes, int n_in,
                              void* d_out, int out_size, void* d_ws, size_t ws_size,
                              hipStream_t stream) {
    const float* z   = (const float*)d_in[0];
    const float* emb = (const float*)d_in[1];
    const float* cs  = (const float*)d_in[2];
    const float* ea  = (const float*)d_in[3];
    float* out = (float*)d_out;
    float* ws  = (float*)d_ws;

    float* esum   = ws + W_ESUM;
    float* counts = ws + W_COUNTS;
    float* enorm  = ws + W_ENORM;
    float* lossp  = ws + W_LOSSP;       // aliases enorm (dead by then)
    int*   widx   = (int*)(ws + W_IDX);

    float* wn = out + O_LOSS;           // scratch slot? no — n must live somewhere:
    // use counts[0..] region? n goes to a dedicated ws float: reuse lossp tail is
    // unsafe (k_nsum reads all 1024). Put n in esum[0]? esum is dead after k_embed
    // reads it... k_embed reads both. Use a float right after W_IDX region:
    wn = ws + (W_IDX + N_ROWS);         // 1 float, total 296961 < round-1 footprint

    k_enorm     <<<KCODES, 64, 0, stream>>>(emb, enorm);
    k_argmin    <<<N_ROWS / 64, 256, 0, stream>>>(z, emb, enorm, widx, out + O_IDX);
    k_zq        <<<1024, 256, 0, stream>>>(z, emb, widx, out + O_ZQ, lossp);
    k_gathersum <<<KCODES, 256, 0, stream>>>(z, widx, esum, counts);
    k_ncs       <<<KCODES / 256, 256, 0, stream>>>(cs, counts, out + O_NCS);
    k_nsum      <<<1, 256, 0, stream>>>(out + O_NCS, lossp, wn, out + O_LOSS);
    k_embed     <<<KCODES, 256, 0, stream>>>(ea, esum, out + O_NCS, wn, out + O_NEA, out + O_NEMB);
}

// Round 3
// 439.162 us; speedup vs baseline: 1.3861x; 1.2639x over previous
//
#include <hip/hip_runtime.h>

// Problem constants
#define N_ROWS   32768      // 64*512 flattened z rows
#define KCODES   1024
#define DDIM     256

// d_out float offsets (outputs concatenated in reference return order)
#define O_ZQ     0                    // 8388608
#define O_LOSS   8388608              // 1
#define O_IDX    8388609              // 32768
#define O_NCS    8421377              // 1024
#define O_NEA    8422401              // 262144
#define O_NEMB   8684545              // 262144

// workspace float offsets
#define W_ESUM   0                    // 262144 floats
#define W_COUNTS 262144               // 1024 floats
#define W_ENORM  263168               // 1024 floats (k_prep -> k_argmin)
#define W_LOSSP  263168               // aliases enorm (dead after argmin)
#define W_IDX    264192               // 32768 ints
// e_hi/e_lo (fp16) live in d_out's O_NEA region (dead until k_embed, the last
// kernel). Placed at O_NEA+3 floats for 16B alignment; spills 3 floats into
// O_NEMB which is also dead until k_embed.

typedef _Float16 half_t;
typedef __attribute__((ext_vector_type(8))) _Float16 half8;
typedef __attribute__((ext_vector_type(4))) _Float16 half4v;
typedef __attribute__((ext_vector_type(4))) float floatx4;

// ---------------------------------------------------------------------------
// ||e_k||^2 + split emb into fp16 hi/lo. 1024 blocks x 64 threads.
__global__ __launch_bounds__(64)
void k_prep(const float* __restrict__ emb, float* __restrict__ enorm,
            half_t* __restrict__ ehi, half_t* __restrict__ elo) {
    int c = blockIdx.x;
    int t = threadIdx.x;
    float4 v = *(const float4*)(emb + c * DDIM + t * 4);
    half4v hi, lo;
    hi[0] = (half_t)v.x; lo[0] = (half_t)(v.x - (float)hi[0]);
    hi[1] = (half_t)v.y; lo[1] = (half_t)(v.y - (float)hi[1]);
    hi[2] = (half_t)v.z; lo[2] = (half_t)(v.z - (float)hi[2]);
    hi[3] = (half_t)v.w; lo[3] = (half_t)(v.w - (float)hi[3]);
    *(half4v*)(ehi + c * DDIM + t * 4) = hi;
    *(half4v*)(elo + c * DDIM + t * 4) = lo;
    float s = v.x * v.x + v.y * v.y + v.z * v.z + v.w * v.w;
    #pragma unroll
    for (int off = 32; off > 0; off >>= 1) s += __shfl_down(s, off);
    if (t == 0) enorm[c] = s;
}

// ---------------------------------------------------------------------------
// MFMA argmin: dist(r,c) = ||e_c||^2 - 2 * z_r . e_c, dot via fp16 hi/lo split
// as K-concat GEMM K'=768: A'=[z_hi|z_hi|z_lo], B'=[e_hi|e_lo|e_hi].
// Block: 64 rows x 1024 codes (8 n-tiles of 128). Wave: 64 rows x 32 codes
// (4 m-tiles x 2 n-subtiles of 16x16x32). LDS: A 64KB (staged once, XOR
// swizzle (row&7) on k8 for conflict-free frag reads) + B dbuf 2x8KB = 80KB
// exactly -> 2 blocks/CU. One barrier per k-step; B prefetched via regs.
__global__ __launch_bounds__(256)
void k_argmin(const float* __restrict__ z, const half_t* __restrict__ ehi,
              const half_t* __restrict__ elo, const float* __restrict__ enorm,
              int* __restrict__ out_idx, float* __restrict__ out_idx_f) {
    __shared__ __align__(16) half_t As[64 * 512];
    __shared__ __align__(16) half_t Bs[2][128 * 32];

    const int tid  = threadIdx.x;
    const int w    = tid >> 6;
    const int lane = tid & 63;
    const int tx   = lane & 15;
    const int quad = lane >> 4;
    const int rbase = blockIdx.x * 64;

    // ---- stage A: read z fp32, split hi/lo in-register, swizzled LDS store
    #pragma unroll
    for (int it = 0; it < 8; ++it) {
        int f   = tid + it * 256;
        int row = f >> 5;             // 0..63
        int g   = f & 31;             // 8-half group within 256 dims
        const float* zp = z + (size_t)(rbase + row) * DDIM + g * 8;
        float4 v0 = *(const float4*)zp;
        float4 v1 = *(const float4*)(zp + 4);
        half8 hi, lo;
        hi[0] = (half_t)v0.x; lo[0] = (half_t)(v0.x - (float)hi[0]);
        hi[1] = (half_t)v0.y; lo[1] = (half_t)(v0.y - (float)hi[1]);
        hi[2] = (half_t)v0.z; lo[2] = (half_t)(v0.z - (float)hi[2]);
        hi[3] = (half_t)v0.w; lo[3] = (half_t)(v0.w - (float)hi[3]);
        hi[4] = (half_t)v1.x; lo[4] = (half_t)(v1.x - (float)hi[4]);
        hi[5] = (half_t)v1.y; lo[5] = (half_t)(v1.y - (float)hi[5]);
        hi[6] = (half_t)v1.z; lo[6] = (half_t)(v1.z - (float)hi[6]);
        hi[7] = (half_t)v1.w; lo[7] = (half_t)(v1.w - (float)hi[7]);
        int sw = row & 7;
        *(half8*)(&As[row * 512 + ((g      ^ sw)) * 8]) = hi;   // k8 = g
        *(half8*)(&As[row * 512 + ((32 + g) ^ sw) * 8]) = lo;   // k8 = 32+g
    }

    // B prefetch machinery. Phase p = nt*24 + ks; seg c = ks>>3:
    //   c==0: hi.hi  c==1: hi.lo  c==2: lo.hi  -> B src: c==1 ? elo : ehi
    auto loadB = [&](int p, float4* bp) {
        int ntq = p / 24, ksq = p - ntq * 24;
        const half_t* src = ((ksq >> 3) == 1) ? elo : ehi;
        const half_t* base = src + (size_t)ntq * 128 * DDIM + (ksq & 7) * 32;
        #pragma unroll
        for (int i = 0; i < 2; ++i) {
            int f = tid + i * 256;
            bp[i] = *(const float4*)(base + (size_t)(f >> 2) * DDIM + (f & 3) * 8);
        }
    };
    auto storeB = [&](int buf, const float4* bp) {
        #pragma unroll
        for (int i = 0; i < 2; ++i) {
            int f = tid + i * 256;
            *(float4*)(&Bs[buf][(f >> 2) * 32 + (f & 3) * 8]) = bp[i];
        }
    };

    float4 bp[2];
    loadB(0, bp);
    storeB(0, bp);
    loadB(1, bp);
    __syncthreads();                  // A staged + Bs[0] ready

    floatx4 zero4 = {0.f, 0.f, 0.f, 0.f};
    floatx4 acc[4][2];
    #pragma unroll
    for (int mt = 0; mt < 4; ++mt) { acc[mt][0] = zero4; acc[mt][1] = zero4; }
    float bd[4][4];
    int   bi[4][4];
    #pragma unroll
    for (int mt = 0; mt < 4; ++mt)
        #pragma unroll
        for (int r = 0; r < 4; ++r) { bd[mt][r] = 3.402823466e38f; bi[mt][r] = 0; }

    int p = 0;
    for (int nt = 0; nt < 8; ++nt) {
        for (int ks = 0; ks < 24; ++ks, ++p) {
            storeB((p + 1) & 1, bp);          // B_{p+1} (buffer free since p-1's barrier)
            if (p + 2 < 192) loadB(p + 2, bp);

            int c   = ks >> 3;
            int k8b = (c == 2 ? 32 : 0) + (ks & 7) * 4;   // A seg: c<2 -> hi, c==2 -> lo
            half8 a[4], b[2];
            #pragma unroll
            for (int mt = 0; mt < 4; ++mt) {
                int row = mt * 16 + tx;
                a[mt] = *(half8*)(&As[row * 512 + ((k8b + quad) ^ (row & 7)) * 8]);
            }
            #pragma unroll
            for (int s = 0; s < 2; ++s)
                b[s] = *(half8*)(&Bs[p & 1][(w * 32 + s * 16 + tx) * 32 + quad * 8]);
            #pragma unroll
            for (int mt = 0; mt < 4; ++mt)
                #pragma unroll
                for (int s = 0; s < 2; ++s)
                    acc[mt][s] = __builtin_amdgcn_mfma_f32_16x16x32_f16(a[mt], b[s], acc[mt][s], 0, 0, 0);
            __syncthreads();
        }
        // fold this 128-code n-tile into running argmin (codes ascending)
        int cb = nt * 128 + w * 32;
        float en0 = enorm[cb + tx];
        float en1 = enorm[cb + 16 + tx];
        #pragma unroll
        for (int mt = 0; mt < 4; ++mt)
            #pragma unroll
            for (int r = 0; r < 4; ++r) {
                float d0 = fmaf(-2.f, acc[mt][0][r], en0);
                float d1 = fmaf(-2.f, acc[mt][1][r], en1);
                if (d0 < bd[mt][r]) { bd[mt][r] = d0; bi[mt][r] = cb + tx; }
                if (d1 < bd[mt][r]) { bd[mt][r] = d1; bi[mt][r] = cb + 16 + tx; }
                acc[mt][0][r] = 0.f;
                acc[mt][1][r] = 0.f;
            }
    }

    // reduce across 16 tx lanes (same rows, different codes); ties -> min index
    #pragma unroll
    for (int mt = 0; mt < 4; ++mt)
        #pragma unroll
        for (int r = 0; r < 4; ++r) {
            float d = bd[mt][r];
            int   b = bi[mt][r];
            #pragma unroll
            for (int off = 8; off > 0; off >>= 1) {
                float od = __shfl_xor(d, off);
                int   ob = __shfl_xor(b, off);
                if (od < d || (od == d && ob < b)) { d = od; b = ob; }
            }
            bd[mt][r] = d; bi[mt][r] = b;
        }

    // cross-wave reduce via LDS (reuse As; all LDS reads done)
    __syncthreads();
    float* sd = (float*)As;           // [64 rows][4 waves]
    int*   si = ((int*)As) + 256;
    if (tx == 0) {
        #pragma unroll
        for (int mt = 0; mt < 4; ++mt)
            #pragma unroll
            for (int r = 0; r < 4; ++r) {
                int row = mt * 16 + quad * 4 + r;   // C-layout: row = quad*4+reg
                sd[row * 4 + w] = bd[mt][r];
                si[row * 4 + w] = bi[mt][r];
            }
    }
    __syncthreads();
    if (tid < 64) {
        int row = tid;
        float d = sd[row * 4];
        int   b = si[row * 4];
        #pragma unroll
        for (int ww = 1; ww < 4; ++ww) {
            float od = sd[row * 4 + ww];
            int   ob = si[row * 4 + ww];
            if (od < d || (od == d && ob < b)) { d = od; b = ob; }
        }
        out_idx[rbase + row]   = b;
        out_idx_f[rbase + row] = (float)b;
    }
}

// ---------------------------------------------------------------------------
// Streaming z_q gather + z_q_st write + commitment-loss partials (no atomics).
__global__ __launch_bounds__(256)
void k_zq(const float* __restrict__ z, const float* __restrict__ emb,
          const int* __restrict__ idx, float* __restrict__ out_zq,
          float* __restrict__ lossp) {
    const int tid = threadIdx.x;
    float l = 0.f;
    #pragma unroll
    for (int u = 0; u < 8; ++u) {
        int g   = blockIdx.x * 2048 + u * 256 + tid;  // float4 index
        int row = g >> 6;
        int c4  = g & 63;
        int k   = idx[row];                            // wave-uniform
        float4 zv = *(const float4*)(z   + (size_t)row * DDIM + c4 * 4);
        float4 ev = *(const float4*)(emb + (size_t)k   * DDIM + c4 * 4);
        float dx = ev.x - zv.x, dy = ev.y - zv.y, dz = ev.z - zv.z, dw = ev.w - zv.w;
        float4 o = { zv.x + dx, zv.y + dy, zv.z + dz, zv.w + dw };  // z + (z_q - z)
        *(float4*)(out_zq + (size_t)g * 4) = o;
        l += dx * dx + dy * dy + dz * dz + dw * dw;
    }
    #pragma unroll
    for (int off = 32; off > 0; off >>= 1) l += __shfl_down(l, off);
    __shared__ float ls[4];
    if ((tid & 63) == 0) ls[tid >> 6] = l;
    __syncthreads();
    if (tid == 0) lossp[blockIdx.x] = ls[0] + ls[1] + ls[2] + ls[3];
}

// ---------------------------------------------------------------------------
// Segment-sum as gather: one block per code, ballot scan, no atomics.
__global__ __launch_bounds__(256)
void k_gathersum(const float* __restrict__ z, const int* __restrict__ idx,
                 float* __restrict__ esum, float* __restrict__ counts) {
    const int code = blockIdx.x;
    const int tid  = threadIdx.x;
    const int w    = tid >> 6;
    const int lane = tid & 63;
    const int seg  = w * (N_ROWS / 4);

    float4 acc = {0.f, 0.f, 0.f, 0.f};
    int cnt = 0;
    #pragma unroll 4
    for (int b = 0; b < N_ROWS / 4; b += 64) {
        int v = idx[seg + b + lane];
        unsigned long long m = __ballot(v == code);
        cnt += __popcll(m);
        while (m) {
            int bit = __builtin_ctzll(m);
            m &= m - 1;
            int rr = seg + b + bit;
            float4 zv = *(const float4*)(z + (size_t)rr * DDIM + lane * 4);
            acc.x += zv.x; acc.y += zv.y; acc.z += zv.z; acc.w += zv.w;
        }
    }

    __shared__ float sacc[4][DDIM];
    __shared__ int   scnt[4];
    *(float4*)(&sacc[w][lane * 4]) = acc;
    if (lane == 0) scnt[w] = cnt;
    __syncthreads();
    float s = sacc[0][tid] + sacc[1][tid] + sacc[2][tid] + sacc[3][tid];
    esum[(size_t)code * DDIM + tid] = s;
    if (tid == 0) counts[code] = (float)(scnt[0] + scnt[1] + scnt[2] + scnt[3]);
}

// ---------------------------------------------------------------------------
// ncs + n + loss in one single-block kernel (merged former k_ncs + k_nsum).
__global__ __launch_bounds__(256)
void k_nsum2(const float* __restrict__ cs_in, const float* __restrict__ counts,
             const float* __restrict__ lossp, float* __restrict__ out_ncs,
             float* __restrict__ n_out, float* __restrict__ loss_out) {
    const int tid = threadIdx.x;
    float v = 0.f, l = 0.f;
    for (int i = tid; i < KCODES; i += 256) {
        float nc = cs_in[i] * 0.99f + 0.01f * counts[i];
        out_ncs[i] = nc;
        v += nc;
        l += lossp[i];
    }
    #pragma unroll
    for (int off = 32; off > 0; off >>= 1) {
        v += __shfl_down(v, off);
        l += __shfl_down(l, off);
    }
    __shared__ float sv[4], sl[4];
    if ((tid & 63) == 0) { sv[tid >> 6] = v; sl[tid >> 6] = l; }
    __syncthreads();
    if (tid == 0) {
        n_out[0]    = sv[0] + sv[1] + sv[2] + sv[3];
        loss_out[0] = 0.25f * ((sl[0] + sl[1] + sl[2] + sl[3]) / 8388608.0f);
    }
}

__global__ __launch_bounds__(256)
void k_embed(const float* __restrict__ ea, const float* __restrict__ esum,
             const float* __restrict__ ncs, const float* __restrict__ n_ws,
             float* __restrict__ out_nea, float* __restrict__ out_nemb) {
    int k = blockIdx.x;
    int d = threadIdx.x;
    size_t off = (size_t)k * DDIM + d;
    float nea = ea[off] * 0.99f + 0.01f * esum[off];
    out_nea[off] = nea;
    float cs = (ncs[k] + 1e-6f) / (n_ws[0] + 0.001024f);   // (ncs+eps)/(n+K*eps)
    out_nemb[off] = nea / cs;
}

// ---------------------------------------------------------------------------
extern "C" void kernel_launch(void* const* d_in, const int* in_sizes, int n_in,
                              void* d_out, int out_size, void* d_ws, size_t ws_size,
                              hipStream_t stream) {
    const float* z   = (const float*)d_in[0];
    const float* emb = (const float*)d_in[1];
    const float* cs  = (const float*)d_in[2];
    const float* ea  = (const float*)d_in[3];
    float* out = (float*)d_out;
    float* ws  = (float*)d_ws;

    float* esum   = ws + W_ESUM;
    float* counts = ws + W_COUNTS;
    float* enorm  = ws + W_ENORM;
    float* lossp  = ws + W_LOSSP;               // aliases enorm (dead post-argmin)
    int*   widx   = (int*)(ws + W_IDX);
    float* wn     = ws + (W_IDX + N_ROWS);      // 1 float

    // e_hi/e_lo fp16 scratch in the dead O_NEA region, 16B-aligned (+3 floats)
    half_t* ehi = (half_t*)(out + O_NEA + 3);
    half_t* elo = ehi + KCODES * DDIM;

    k_prep      <<<KCODES, 64, 0, stream>>>(emb, enorm, ehi, elo);
    k_argmin    <<<N_ROWS / 64, 256, 0, stream>>>(z, ehi, elo, enorm, widx, out + O_IDX);
    k_zq        <<<1024, 256, 0, stream>>>(z, emb, widx, out + O_ZQ, lossp);
    k_gathersum <<<KCODES, 256, 0, stream>>>(z, widx, esum, counts);
    k_nsum2     <<<1, 256, 0, stream>>>(cs, counts, lossp, out + O_NCS, wn, out + O_LOSS);
    k_embed     <<<KCODES, 256, 0, stream>>>(ea, esum, out + O_NCS, wn, out + O_NEA, out + O_NEMB);
}

// Round 4
// 334.968 us; speedup vs baseline: 1.8173x; 1.3111x over previous
//
#include <hip/hip_runtime.h>

// Problem constants
#define N_ROWS   32768      // 64*512 flattened z rows
#define KCODES   1024
#define DDIM     256

// d_out float offsets (outputs concatenated in reference return order)
#define O_ZQ     0                    // 8388608
#define O_LOSS   8388608              // 1
#define O_IDX    8388609              // 32768
#define O_NCS    8421377              // 1024
#define O_NEA    8422401              // 262144
#define O_NEMB   8684545              // 262144

// workspace float offsets
#define W_ESUM   0                    // 262144 floats
#define W_COUNTS 262144               // 1024 floats
#define W_ENORM  263168               // 1024 floats (k_prep -> k_argmin; NOT aliased)
#define W_IDX    264192               // 32768 ints
#define W_N      296960               // 1 float
#define W_LOSSP  297024               // 512 floats (k_argmin epilogue -> k_nsum2)
// total 297536 floats ~= 1.135 MB

typedef _Float16 half_t;
typedef __attribute__((ext_vector_type(8))) _Float16 half8;
typedef __attribute__((ext_vector_type(4))) _Float16 half4v;
typedef __attribute__((ext_vector_type(4))) float floatx4;

// ---------------------------------------------------------------------------
// ||e_k||^2 + split emb into fp16 hi/lo. 1024 blocks x 64 threads.
__global__ __launch_bounds__(64)
void k_prep(const float* __restrict__ emb, float* __restrict__ enorm,
            half_t* __restrict__ ehi, half_t* __restrict__ elo) {
    int c = blockIdx.x;
    int t = threadIdx.x;
    float4 v = *(const float4*)(emb + c * DDIM + t * 4);
    half4v hi, lo;
    hi[0] = (half_t)v.x; lo[0] = (half_t)(v.x - (float)hi[0]);
    hi[1] = (half_t)v.y; lo[1] = (half_t)(v.y - (float)hi[1]);
    hi[2] = (half_t)v.z; lo[2] = (half_t)(v.z - (float)hi[2]);
    hi[3] = (half_t)v.w; lo[3] = (half_t)(v.w - (float)hi[3]);
    *(half4v*)(ehi + c * DDIM + t * 4) = hi;
    *(half4v*)(elo + c * DDIM + t * 4) = lo;
    float s = v.x * v.x + v.y * v.y + v.z * v.z + v.w * v.w;
    #pragma unroll
    for (int off = 32; off > 0; off >>= 1) s += __shfl_down(s, off);
    if (t == 0) enorm[c] = s;
}

// ---------------------------------------------------------------------------
// MFMA argmin, barrier-free K-loop + fused z_q epilogue.
// dist(r,c) = ||e_c||^2 - 2 * z_r . e_c; dot via fp16 hi/lo K-concat (K'=768):
// segments c=0: z_hi.e_hi, c=1: z_hi.e_lo, c=2: z_lo.e_hi.
// Block: 64 rows, 256 thr. A (z split) in LDS 64KB, staged once, XOR-swizzled.
// Wave w owns codes [w*256,(w+1)*256): 4 groups x (4 m x 4 n) 16x16x32 MFMAs.
// B-frags loaded straight from global (L2-resident, 1MB) into registers with
// 1-step double buffer -- ZERO barriers in the K-loop (round-3 killer was the
// per-phase __syncthreads vmcnt(0) drain: MfmaUtil 8.7%).
__global__ __launch_bounds__(256)
void k_argmin(const float* __restrict__ z, const half_t* __restrict__ ehi,
              const half_t* __restrict__ elo, const float* __restrict__ enorm,
              const float* __restrict__ embf,
              int* __restrict__ out_idx, float* __restrict__ out_idx_f,
              float* __restrict__ out_zq, float* __restrict__ lossp) {
    __shared__ __align__(16) half_t As[64 * 512];   // 64 KB

    const int tid  = threadIdx.x;
    const int w    = tid >> 6;
    const int lane = tid & 63;
    const int tx   = lane & 15;
    const int quad = lane >> 4;
    const int rbase = blockIdx.x * 64;

    // ---- stage A: read z fp32, split hi/lo in-register, swizzled LDS store
    #pragma unroll
    for (int it = 0; it < 8; ++it) {
        int f   = tid + it * 256;
        int row = f >> 5;             // 0..63
        int g   = f & 31;             // 8-half group within 256 dims
        const float* zp = z + (size_t)(rbase + row) * DDIM + g * 8;
        float4 v0 = *(const float4*)zp;
        float4 v1 = *(const float4*)(zp + 4);
        half8 hi, lo;
        hi[0] = (half_t)v0.x; lo[0] = (half_t)(v0.x - (float)hi[0]);
        hi[1] = (half_t)v0.y; lo[1] = (half_t)(v0.y - (float)hi[1]);
        hi[2] = (half_t)v0.z; lo[2] = (half_t)(v0.z - (float)hi[2]);
        hi[3] = (half_t)v0.w; lo[3] = (half_t)(v0.w - (float)hi[3]);
        hi[4] = (half_t)v1.x; lo[4] = (half_t)(v1.x - (float)hi[4]);
        hi[5] = (half_t)v1.y; lo[5] = (half_t)(v1.y - (float)hi[5]);
        hi[6] = (half_t)v1.z; lo[6] = (half_t)(v1.z - (float)hi[6]);
        hi[7] = (half_t)v1.w; lo[7] = (half_t)(v1.w - (float)hi[7]);
        int sw = row & 7;
        *(half8*)(&As[row * 512 + ((g      ^ sw)) * 8]) = hi;   // k8 = g
        *(half8*)(&As[row * 512 + ((32 + g) ^ sw) * 8]) = lo;   // k8 = 32+g
    }
    __syncthreads();                  // the ONLY main-loop barrier

    floatx4 zero4 = {0.f, 0.f, 0.f, 0.f};
    float bd[4][4];
    int   bi[4][4];
    #pragma unroll
    for (int mt = 0; mt < 4; ++mt)
        #pragma unroll
        for (int r = 0; r < 4; ++r) { bd[mt][r] = 3.402823466e38f; bi[mt][r] = 0; }

    for (int g = 0; g < 4; ++g) {
        const int cb = w * 256 + g * 64;
        floatx4 acc[4][4];
        #pragma unroll
        for (int mt = 0; mt < 4; ++mt)
            #pragma unroll
            for (int ns = 0; ns < 4; ++ns) acc[mt][ns] = zero4;

        size_t crow[4];
        #pragma unroll
        for (int ns = 0; ns < 4; ++ns)
            crow[ns] = (size_t)(cb + ns * 16 + tx) * DDIM + quad * 8;

        half8 bc[4], bn[4];
        #pragma unroll
        for (int ns = 0; ns < 4; ++ns)           // ks=0: c=0, src=ehi, koff=0
            bc[ns] = *(const half8*)(ehi + crow[ns]);

        #pragma unroll
        for (int ks = 0; ks < 24; ++ks) {
            const int c   = ks >> 3;
            const int k8b = (c == 2 ? 32 : 0) + (ks & 7) * 4;
            half8 a[4];
            #pragma unroll
            for (int mt = 0; mt < 4; ++mt) {
                int row = mt * 16 + tx;
                a[mt] = *(half8*)(&As[row * 512 + ((k8b + quad) ^ (row & 7)) * 8]);
            }
            if (ks < 23) {                        // prefetch next k-step's B
                const int ksn  = ks + 1;
                const int cn   = ksn >> 3;
                const half_t* srcn = (cn == 1) ? elo : ehi;
                const int koffn = (ksn & 7) * 32;
                #pragma unroll
                for (int ns = 0; ns < 4; ++ns)
                    bn[ns] = *(const half8*)(srcn + crow[ns] + koffn);
            }
            #pragma unroll
            for (int mt = 0; mt < 4; ++mt)
                #pragma unroll
                for (int ns = 0; ns < 4; ++ns)
                    acc[mt][ns] = __builtin_amdgcn_mfma_f32_16x16x32_f16(a[mt], bc[ns], acc[mt][ns], 0, 0, 0);
            #pragma unroll
            for (int ns = 0; ns < 4; ++ns) bc[ns] = bn[ns];
        }

        // fold group into running argmin (codes ascending; strict <, min-index)
        #pragma unroll
        for (int ns = 0; ns < 4; ++ns) {
            float en = enorm[cb + ns * 16 + tx];
            int   cc = cb + ns * 16 + tx;
            #pragma unroll
            for (int mt = 0; mt < 4; ++mt)
                #pragma unroll
                for (int r = 0; r < 4; ++r) {
                    float d = fmaf(-2.f, acc[mt][ns][r], en);
                    if (d < bd[mt][r]) { bd[mt][r] = d; bi[mt][r] = cc; }
                }
        }
    }

    // reduce across 16 tx lanes (same row, different codes); ties -> min index
    #pragma unroll
    for (int mt = 0; mt < 4; ++mt)
        #pragma unroll
        for (int r = 0; r < 4; ++r) {
            float d = bd[mt][r];
            int   b = bi[mt][r];
            #pragma unroll
            for (int off = 8; off > 0; off >>= 1) {
                float od = __shfl_xor(d, off);
                int   ob = __shfl_xor(b, off);
                if (od < d || (od == d && ob < b)) { d = od; b = ob; }
            }
            bd[mt][r] = d; bi[mt][r] = b;
        }

    // cross-wave reduce via LDS (reuse As)
    __syncthreads();
    float* sd   = (float*)As;          // [64 rows][4 waves]
    int*   si   = ((int*)As) + 256;
    int*   sidx = ((int*)As) + 512;    // final idx per row
    if (tx == 0) {
        #pragma unroll
        for (int mt = 0; mt < 4; ++mt)
            #pragma unroll
            for (int r = 0; r < 4; ++r) {
                int row = mt * 16 + quad * 4 + r;   // C-layout: row = quad*4+reg
                sd[row * 4 + w] = bd[mt][r];
                si[row * 4 + w] = bi[mt][r];
            }
    }
    __syncthreads();
    if (tid < 64) {
        int row = tid;
        float d = sd[row * 4];
        int   b = si[row * 4];
        #pragma unroll
        for (int ww = 1; ww < 4; ++ww) {
            float od = sd[row * 4 + ww];
            int   ob = si[row * 4 + ww];
            if (od < d || (od == d && ob < b)) { d = od; b = ob; }
        }
        out_idx[rbase + row]   = b;
        out_idx_f[rbase + row] = (float)b;
        sidx[row] = b;
    }
    __syncthreads();

    // ---- fused z_q epilogue: z_q_st write + commitment-loss partial
    float l = 0.f;
    #pragma unroll
    for (int u = 0; u < 16; ++u) {
        int gi  = tid + u * 256;       // 0..4095 float4s = 64 rows x 64
        int row = gi >> 6;
        int c4  = gi & 63;
        int k   = sidx[row];           // wave-uniform
        float4 zv = *(const float4*)(z    + (size_t)(rbase + row) * DDIM + c4 * 4);
        float4 ev = *(const float4*)(embf + (size_t)k * DDIM + c4 * 4);
        float dx = ev.x - zv.x, dy = ev.y - zv.y, dz = ev.z - zv.z, dw = ev.w - zv.w;
        float4 o = { zv.x + dx, zv.y + dy, zv.z + dz, zv.w + dw };  // z + (z_q - z)
        *(float4*)(out_zq + (size_t)(rbase + row) * DDIM + c4 * 4) = o;
        l += dx * dx + dy * dy + dz * dz + dw * dw;
    }
    #pragma unroll
    for (int off = 32; off > 0; off >>= 1) l += __shfl_down(l, off);
    __shared__ float ls[4];
    if (lane == 0) ls[w] = l;
    __syncthreads();
    if (tid == 0) lossp[blockIdx.x] = ls[0] + ls[1] + ls[2] + ls[3];
}

// ---------------------------------------------------------------------------
// Segment-sum as gather: one block per code, ballot scan, no atomics.
__global__ __launch_bounds__(256)
void k_gathersum(const float* __restrict__ z, const int* __restrict__ idx,
                 float* __restrict__ esum, float* __restrict__ counts) {
    const int code = blockIdx.x;
    const int tid  = threadIdx.x;
    const int w    = tid >> 6;
    const int lane = tid & 63;
    const int seg  = w * (N_ROWS / 4);

    float4 acc = {0.f, 0.f, 0.f, 0.f};
    int cnt = 0;
    #pragma unroll 4
    for (int b = 0; b < N_ROWS / 4; b += 64) {
        int v = idx[seg + b + lane];
        unsigned long long m = __ballot(v == code);
        cnt += __popcll(m);
        while (m) {
            int bit = __builtin_ctzll(m);
            m &= m - 1;
            int rr = seg + b + bit;
            float4 zv = *(const float4*)(z + (size_t)rr * DDIM + lane * 4);
            acc.x += zv.x; acc.y += zv.y; acc.z += zv.z; acc.w += zv.w;
        }
    }

    __shared__ float sacc[4][DDIM];
    __shared__ int   scnt[4];
    *(float4*)(&sacc[w][lane * 4]) = acc;
    if (lane == 0) scnt[w] = cnt;
    __syncthreads();
    float s = sacc[0][tid] + sacc[1][tid] + sacc[2][tid] + sacc[3][tid];
    esum[(size_t)code * DDIM + tid] = s;
    if (tid == 0) counts[code] = (float)(scnt[0] + scnt[1] + scnt[2] + scnt[3]);
}

// ---------------------------------------------------------------------------
// ncs + n + loss in one single-block kernel.
__global__ __launch_bounds__(256)
void k_nsum2(const float* __restrict__ cs_in, const float* __restrict__ counts,
             const float* __restrict__ lossp, float* __restrict__ out_ncs,
             float* __restrict__ n_out, float* __restrict__ loss_out) {
    const int tid = threadIdx.x;
    float v = 0.f, l = 0.f;
    for (int i = tid; i < KCODES; i += 256) {
        float nc = cs_in[i] * 0.99f + 0.01f * counts[i];
        out_ncs[i] = nc;
        v += nc;
    }
    for (int i = tid; i < 512; i += 256) l += lossp[i];
    #pragma unroll
    for (int off = 32; off > 0; off >>= 1) {
        v += __shfl_down(v, off);
        l += __shfl_down(l, off);
    }
    __shared__ float sv[4], sl[4];
    if ((tid & 63) == 0) { sv[tid >> 6] = v; sl[tid >> 6] = l; }
    __syncthreads();
    if (tid == 0) {
        n_out[0]    = sv[0] + sv[1] + sv[2] + sv[3];
        loss_out[0] = 0.25f * ((sl[0] + sl[1] + sl[2] + sl[3]) / 8388608.0f);
    }
}

__global__ __launch_bounds__(256)
void k_embed(const float* __restrict__ ea, const float* __restrict__ esum,
             const float* __restrict__ ncs, const float* __restrict__ n_ws,
             float* __restrict__ out_nea, float* __restrict__ out_nemb) {
    int k = blockIdx.x;
    int d = threadIdx.x;
    size_t off = (size_t)k * DDIM + d;
    float nea = ea[off] * 0.99f + 0.01f * esum[off];
    out_nea[off] = nea;
    float cs = (ncs[k] + 1e-6f) / (n_ws[0] + 0.001024f);   // (ncs+eps)/(n+K*eps)
    out_nemb[off] = nea / cs;
}

// ---------------------------------------------------------------------------
extern "C" void kernel_launch(void* const* d_in, const int* in_sizes, int n_in,
                              void* d_out, int out_size, void* d_ws, size_t ws_size,
                              hipStream_t stream) {
    const float* z   = (const float*)d_in[0];
    const float* emb = (const float*)d_in[1];
    const float* cs  = (const float*)d_in[2];
    const float* ea  = (const float*)d_in[3];
    float* out = (float*)d_out;
    float* ws  = (float*)d_ws;

    float* esum   = ws + W_ESUM;
    float* counts = ws + W_COUNTS;
    float* enorm  = ws + W_ENORM;
    int*   widx   = (int*)(ws + W_IDX);
    float* wn     = ws + W_N;
    float* lossp  = ws + W_LOSSP;

    // e_hi/e_lo fp16 scratch in the dead O_NEA region, 16B-aligned (+3 floats)
    half_t* ehi = (half_t*)(out + O_NEA + 3);
    half_t* elo = ehi + KCODES * DDIM;

    k_prep      <<<KCODES, 64, 0, stream>>>(emb, enorm, ehi, elo);
    k_argmin    <<<N_ROWS / 64, 256, 0, stream>>>(z, ehi, elo, enorm, emb,
                                                  widx, out + O_IDX, out + O_ZQ, lossp);
    k_gathersum <<<KCODES, 256, 0, stream>>>(z, widx, esum, counts);
    k_nsum2     <<<1, 256, 0, stream>>>(cs, counts, lossp, out + O_NCS, wn, out + O_LOSS);
    k_embed     <<<KCODES, 256, 0, stream>>>(ea, esum, out + O_NCS, wn, out + O_NEA, out + O_NEMB);
}